// Round 11
// baseline (2451.795 us; speedup 1.0000x reference)
//
#include <hip/hip_runtime.h>
#include <cstdint>

// ---------------- fast device math (raw v_exp_f32 / v_rcp_f32) ----------------
__device__ __forceinline__ float fexp2(float x) { return __builtin_amdgcn_exp2f(x); }
__device__ __forceinline__ float frcp(float x)  { return __builtin_amdgcn_rcpf(x); }

__device__ __forceinline__ float fast_tanh(float x) {
    x = fminf(15.0f, fmaxf(-15.0f, x));
    float E = fexp2(x * 2.8853900817779268f);   // exp(2x) = 2^(2x*log2e)
    float d = E + 1.0f;
    float r = frcp(d);
    r = r * (2.0f - d * r);                      // Newton -> ~fp32 precise
    return (E - 1.0f) * r;
}

// ---------------- tiled fp32 GEMM v1: 64x64 tile, 4x4 micro (small-N layers) --
#define BM 64
#define BN 64
#define BK 16

template<bool TANH>
__global__ __launch_bounds__(256) void gemm_bias(
    const float* __restrict__ A, const float* __restrict__ W,
    const float* __restrict__ bias, float* __restrict__ C,
    int M, int N, int K)
{
    __shared__ float As[BK][BM + 4];
    __shared__ float Bs[BK][BN + 4];

    const int tid = threadIdx.x;
    const int tx = tid & 15;
    const int ty = tid >> 4;
    const int m0 = blockIdx.y * BM;
    const int n0 = blockIdx.x * BN;

    float acc[4][4] = {};

    for (int k0 = 0; k0 < K; k0 += BK) {
        #pragma unroll
        for (int ld = 0; ld < 4; ++ld) {
            int e  = tid + ld * 256;
            int kk = e & 15, mm = e >> 4;
            int kg = k0 + kk;
            As[kk][mm] = (kg < K) ? A[(size_t)(m0 + mm) * K + kg] : 0.0f;
        }
        #pragma unroll
        for (int ld = 0; ld < 4; ++ld) {
            int e  = tid + ld * 256;
            int nn = e & 63, kk = e >> 6;
            int kg = k0 + kk, ng = n0 + nn;
            Bs[kk][nn] = (kg < K && ng < N) ? W[(size_t)kg * N + ng] : 0.0f;
        }
        __syncthreads();

        #pragma unroll
        for (int kk = 0; kk < BK; ++kk) {
            float4 a  = *(const float4*)&As[kk][ty * 4];
            float4 bq = *(const float4*)&Bs[kk][tx * 4];
            float av[4] = {a.x, a.y, a.z, a.w};
            float bv[4] = {bq.x, bq.y, bq.z, bq.w};
            #pragma unroll
            for (int i2 = 0; i2 < 4; ++i2)
                #pragma unroll
                for (int j2 = 0; j2 < 4; ++j2)
                    acc[i2][j2] += av[i2] * bv[j2];
        }
        __syncthreads();
    }

    const int cbase = n0 + tx * 4;
    if (cbase >= N) return;

    float bb[4];
    if (cbase + 3 < N) {
        float4 b4 = *(const float4*)&bias[cbase];
        bb[0] = b4.x; bb[1] = b4.y; bb[2] = b4.z; bb[3] = b4.w;
    } else {
        #pragma unroll
        for (int e = 0; e < 4; ++e) bb[e] = (cbase + e < N) ? bias[cbase + e] : 0.0f;
    }

    #pragma unroll
    for (int i2 = 0; i2 < 4; ++i2) {
        int row = m0 + ty * 4 + i2;
        float o[4];
        #pragma unroll
        for (int j2 = 0; j2 < 4; ++j2) {
            float v = acc[i2][j2] + bb[j2];
            o[j2] = TANH ? fast_tanh(v) : v;
        }
        if (cbase + 3 < N) {
            float4 o4 = {o[0], o[1], o[2], o[3]};
            *(float4*)&C[(size_t)row * N + cbase] = o4;
        } else {
            #pragma unroll
            for (int j2 = 0; j2 < 4; ++j2)
                if (cbase + j2 < N) C[(size_t)row * N + cbase + j2] = o[j2];
        }
    }
}

// ---------------- fp32 GEMM 128x128, 8x8 micro (the two K=500,N=500 layers) ---
// Per lane per kk: 4x ds_read_b128 + 64 FMA -> FMA-issue-bound (~128 cyc FMA
// vs ~48-76 cyc LDS incl. 4-way read aliasing). 4 waves/block, 512 blocks.
#define TBM 128
#define TBN 128
#define TBK 16

template<bool TANH>
__global__ __launch_bounds__(256) void gemm128(
    const float* __restrict__ A, const float* __restrict__ W,
    const float* __restrict__ bias, float* __restrict__ C,
    int M, int N, int K)
{
    __shared__ float As[TBK][TBM + 4];
    __shared__ float Bs[TBK][TBN + 4];

    const int tid = threadIdx.x;
    const int tx = tid & 15;          // col-oct
    const int ty = tid >> 4;          // row-oct
    const int m0 = blockIdx.y * TBM;
    const int n0 = blockIdx.x * TBN;

    float acc[8][8] = {};

    for (int k0 = 0; k0 < K; k0 += TBK) {
        #pragma unroll
        for (int ld = 0; ld < 8; ++ld) {
            int e = tid + ld * 256;          // 0..2047
            int kk = e & 15, mm = e >> 4;
            int kg = k0 + kk;
            As[kk][mm] = (kg < K) ? A[(size_t)(m0 + mm) * K + kg] : 0.0f;
        }
        #pragma unroll
        for (int ld = 0; ld < 8; ++ld) {
            int e = tid + ld * 256;
            int nn = e & 127, kk = e >> 7;
            int kg = k0 + kk, ng = n0 + nn;
            Bs[kk][nn] = (kg < K && ng < N) ? W[(size_t)kg * N + ng] : 0.0f;
        }
        __syncthreads();

        #pragma unroll
        for (int kk = 0; kk < TBK; ++kk) {
            float4 a0 = *(const float4*)&As[kk][ty * 8];
            float4 a1 = *(const float4*)&As[kk][ty * 8 + 4];
            float4 b0 = *(const float4*)&Bs[kk][tx * 8];
            float4 b1 = *(const float4*)&Bs[kk][tx * 8 + 4];
            float av[8] = {a0.x, a0.y, a0.z, a0.w, a1.x, a1.y, a1.z, a1.w};
            float bv[8] = {b0.x, b0.y, b0.z, b0.w, b1.x, b1.y, b1.z, b1.w};
            #pragma unroll
            for (int i2 = 0; i2 < 8; ++i2)
                #pragma unroll
                for (int j2 = 0; j2 < 8; ++j2)
                    acc[i2][j2] = fmaf(av[i2], bv[j2], acc[i2][j2]);
        }
        __syncthreads();
    }

    const int cb0 = n0 + tx * 8;
    if (cb0 >= N) return;
    float bb[8];
    #pragma unroll
    for (int e = 0; e < 8; ++e) bb[e] = (cb0 + e < N) ? bias[cb0 + e] : 0.0f;

    #pragma unroll
    for (int i2 = 0; i2 < 8; ++i2) {
        int row = m0 + ty * 8 + i2;
        float o[8];
        #pragma unroll
        for (int j2 = 0; j2 < 8; ++j2) {
            float v = acc[i2][j2] + bb[j2];
            o[j2] = TANH ? fast_tanh(v) : v;
        }
        if (cb0 + 7 < N) {
            float4 o4a = {o[0], o[1], o[2], o[3]};
            float4 o4b = {o[4], o[5], o[6], o[7]};
            *(float4*)&C[(size_t)row * N + cb0]     = o4a;
            *(float4*)&C[(size_t)row * N + cb0 + 4] = o4b;
        } else {
            #pragma unroll
            for (int j2 = 0; j2 < 8; ++j2)
                if (cb0 + j2 < N) C[(size_t)row * N + cb0 + j2] = o[j2];
        }
    }
}

// ---------------- decoder layer 1 (K=4) --------------------------------------
__global__ __launch_bounds__(256) void dec_l1(
    const float* __restrict__ Mo, const float* __restrict__ Wd,
    const float* __restrict__ bd, float* __restrict__ O)
{
    int idx = blockIdx.x * 256 + threadIdx.x;
    int r  = idx / 125;
    int c4 = (idx % 125) * 4;
    float4 m = *(const float4*)&Mo[(size_t)r * 4];
    float4 w0 = *(const float4*)&Wd[0 * 500 + c4];
    float4 w1 = *(const float4*)&Wd[1 * 500 + c4];
    float4 w2 = *(const float4*)&Wd[2 * 500 + c4];
    float4 w3 = *(const float4*)&Wd[3 * 500 + c4];
    float4 b  = *(const float4*)&bd[c4];
    float o0 = b.x + m.x * w0.x + m.y * w1.x + m.z * w2.x + m.w * w3.x;
    float o1 = b.y + m.x * w0.y + m.y * w1.y + m.z * w2.y + m.w * w3.y;
    float o2 = b.z + m.x * w0.z + m.y * w1.z + m.z * w2.z + m.w * w3.z;
    float o3 = b.w + m.x * w0.w + m.y * w1.w + m.z * w2.w + m.w * w3.w;
    float4 o = {fast_tanh(o0), fast_tanh(o1), fast_tanh(o2), fast_tanh(o3)};
    *(float4*)&O[(size_t)r * 500 + c4] = o;
}

// ---------------- LTC scan: split-j butterfly (R8 exact, best: 1532us) -------
// 1 block/batch, 8 waves (512 thr). Wave w owns OUTPUT slice j in [8w,8w+8).
// Lane l: jl = l&7 (j = 8w+jl), ig = l>>3 (presynaptic i in [8ig, 8ig+8)).
// Per unfold: read v[64] from LDS (2x b128), 8 syn (fma+exp+rcp), butterfly
// reduce over ig bits (shfl_xor 8/16/32), compute vj, ig==0 writes v, ONE
// barrier. Latency-bound at ~1197 cyc/unfold; issue cuts proven neutral
// (R7 4-wide batch-rcp regressed, R9 pairwise-rcp neutral) -> keep simple.
#define SEQ_T 512

__global__ __launch_bounds__(512, 2) void ltc_scan(
    const float* __restrict__ h,       // [32][512][20]
    const float* __restrict__ gleak, const float* __restrict__ vleak,
    const float* __restrict__ cm,
    const float* __restrict__ w,  const float* __restrict__ mu,
    const float* __restrict__ sg, const float* __restrict__ erev,
    const float* __restrict__ sw,  const float* __restrict__ smu,
    const float* __restrict__ ssg, const float* __restrict__ serev,
    const float* __restrict__ in_w, const float* __restrict__ in_b,
    const float* __restrict__ out_w, const float* __restrict__ out_b,
    float* __restrict__ motor)         // [32][512][4]
{
    const int b   = blockIdx.x;
    const int tid = threadIdx.x;
    const int w8  = tid >> 6;          // wave 0..7
    const int l   = tid & 63;
    const int jl  = l & 7;
    const int ig  = l >> 3;
    const int j   = 8 * w8 + jl;       // this lane's output unit

    const float LOG2E = 1.4426950408889634f;

    __shared__ float vbuf[2][64];

    // unfold params for (i = 8*ig + r, j)
    float A1[8], B1[8], Wp[8], WE[8];
    #pragma unroll
    for (int r = 0; r < 8; ++r) {
        int i = 8 * ig + r;
        float s = sg[i * 64 + j];
        A1[r] = s * LOG2E;
        B1[r] = mu[i * 64 + j] * s * LOG2E;
        Wp[r] = w[i * 64 + j];
        WE[r] = Wp[r] * erev[i * 64 + j];
    }
    // sensory: lane handles i in {ig, ig+8, ig+16 if ig<4} for its j
    float sA[3], sB[3], sWp[3], sWE[3], uw[3], ub[3];
    int   sI[3];
    #pragma unroll
    for (int r = 0; r < 3; ++r) {
        int i = ig + 8 * r;
        bool live = (i < 20);
        sI[r] = live ? i : 0;
        float s = ssg[sI[r] * 64 + j];
        sA[r]  = s * LOG2E;
        sB[r]  = smu[sI[r] * 64 + j] * s * LOG2E;
        sWp[r] = live ? sw[sI[r] * 64 + j] : 0.0f;
        sWE[r] = live ? sWp[r] * serev[sI[r] * 64 + j] : 0.0f;
        uw[r]  = in_w[sI[r]];
        ub[r]  = in_b[sI[r]];
    }

    const float cmt  = cm[j] * 6.0f;
    const float gl   = gleak[j];
    const float glvl = gl * vleak[j];
    const float gle  = cmt + gl + 1e-8f;
    const float ow   = out_w[j & 3], ob = out_b[j & 3];

    float vj = 0.0f;                   // this lane's own v_j
    const float* hb = h + (size_t)b * SEQ_T * 20;
    float* mb = motor + (size_t)b * SEQ_T * 4;

    float u_cur[3], u_nxt[3];
    #pragma unroll
    for (int r = 0; r < 3; ++r) u_cur[r] = hb[sI[r]];

    if (tid < 64) vbuf[0][tid] = 0.0f;
    __syncthreads();

    int cur = 0;
    for (int t = 0; t < SEQ_T; ++t) {
        int tn = (t + 1 < SEQ_T) ? (t + 1) : t;
        #pragma unroll
        for (int r = 0; r < 3; ++r) u_nxt[r] = hb[tn * 20 + sI[r]];

        // sensory per-lane partial, butterfly-reduced once per t
        float ns = 0.0f, ds = 0.0f;
        #pragma unroll
        for (int r = 0; r < 3; ++r) {
            float ui = fmaf(u_cur[r], uw[r], ub[r]);
            float x  = sB[r] - ui * sA[r];
            float E  = fexp2(x);
            float s  = frcp(1.0f + E);
            ns = fmaf(sWE[r], s, ns);
            ds = fmaf(sWp[r], s, ds);
        }
        ns += __shfl_xor(ns, 8);  ds += __shfl_xor(ds, 8);
        ns += __shfl_xor(ns, 16); ds += __shfl_xor(ds, 16);
        ns += __shfl_xor(ns, 32); ds += __shfl_xor(ds, 32);

        #pragma unroll 1
        for (int uf = 0; uf < 6; ++uf) {
            float4 va = *(const float4*)&vbuf[cur][8 * ig];
            float4 vc = *(const float4*)&vbuf[cur][8 * ig + 4];
            float vv[8] = {va.x, va.y, va.z, va.w, vc.x, vc.y, vc.z, vc.w};

            float an = 0.0f, ad = 0.0f;
            #pragma unroll
            for (int r = 0; r < 8; ++r) {
                float x = fmaf(-vv[r], A1[r], B1[r]);
                float E = fexp2(x);
                float s = frcp(1.0f + E);
                an = fmaf(WE[r], s, an);
                ad = fmaf(Wp[r], s, ad);
            }
            // butterfly over ig bits (8,16,32): intra-wave, no LDS
            an += __shfl_xor(an, 8);  ad += __shfl_xor(ad, 8);
            an += __shfl_xor(an, 16); ad += __shfl_xor(ad, 16);
            an += __shfl_xor(an, 32); ad += __shfl_xor(ad, 32);

            float num = fmaf(cmt, vj, glvl) + an + ns;
            float den = gle + ad + ds;
            vj = num * frcp(den);

            if (ig == 0) vbuf[cur ^ 1][j] = vj;
            __syncthreads();
            cur ^= 1;
        }

        if (w8 == 0 && ig == 0 && jl < 4) mb[t * 4 + jl] = fmaf(vj, ow, ob);

        #pragma unroll
        for (int r = 0; r < 3; ++r) u_cur[r] = u_nxt[r];
    }
}

// ---------------- launch --------------------------------------------------
extern "C" void kernel_launch(void* const* d_in, const int* in_sizes, int n_in,
                              void* d_out, int out_size, void* d_ws, size_t ws_size,
                              hipStream_t stream) {
    const float* x      = (const float*)d_in[0];
    const float* enc_w0 = (const float*)d_in[1];
    const float* enc_b0 = (const float*)d_in[2];
    const float* enc_w1 = (const float*)d_in[3];
    const float* enc_b1 = (const float*)d_in[4];
    const float* enc_w2 = (const float*)d_in[5];
    const float* enc_b2 = (const float*)d_in[6];
    const float* dec_w0 = (const float*)d_in[7];
    const float* dec_b0 = (const float*)d_in[8];
    const float* dec_w1 = (const float*)d_in[9];
    const float* dec_b1 = (const float*)d_in[10];
    const float* dec_w2 = (const float*)d_in[11];
    const float* dec_b2 = (const float*)d_in[12];
    const float* gleak  = (const float*)d_in[13];
    const float* vleak  = (const float*)d_in[14];
    const float* cm     = (const float*)d_in[15];
    const float* w      = (const float*)d_in[16];
    const float* mu     = (const float*)d_in[17];
    const float* sigma  = (const float*)d_in[18];
    const float* erev   = (const float*)d_in[19];
    const float* sw     = (const float*)d_in[20];
    const float* smu    = (const float*)d_in[21];
    const float* ssigma = (const float*)d_in[22];
    const float* serev  = (const float*)d_in[23];
    const float* in_w   = (const float*)d_in[24];
    const float* in_b   = (const float*)d_in[25];
    const float* out_w  = (const float*)d_in[26];
    const float* out_b  = (const float*)d_in[27];

    float* ws   = (float*)d_ws;
    float* buf1 = ws;                       // 16384*500
    float* buf2 = ws + 8192000;             // 16384*500
    float* hbuf = ws + 16384000;            // 16384*20
    float* mbuf = ws + 16384000 + 327680;   // 16384*4

    dim3 blk(256);
    // encoder
    gemm_bias<true ><<<dim3(8, 256), blk, 0, stream>>>(x,    enc_w0, enc_b0, buf1, 16384, 500, 39);
    gemm128 <true ><<<dim3(4, 128), blk, 0, stream>>>(buf1, enc_w1, enc_b1, buf2, 16384, 500, 500);
    gemm_bias<false><<<dim3(1, 256), blk, 0, stream>>>(buf2, enc_w2, enc_b2, hbuf, 16384, 20, 500);
    // LTC scan
    ltc_scan<<<dim3(32), dim3(512), 0, stream>>>(hbuf, gleak, vleak, cm, w, mu, sigma, erev,
                                                 sw, smu, ssigma, serev, in_w, in_b, out_w, out_b, mbuf);
    // decoder
    dec_l1<<<dim3(8000), blk, 0, stream>>>(mbuf, dec_w0, dec_b0, buf1);
    gemm128 <true ><<<dim3(4, 128), blk, 0, stream>>>(buf1, dec_w1, dec_b1, buf2, 16384, 500, 500);
    gemm_bias<false><<<dim3(1, 256), blk, 0, stream>>>(buf2, dec_w2, dec_b2, (float*)d_out, 16384, 30, 500);
}

// Round 13
// 1875.976 us; speedup vs baseline: 1.3069x; 1.3069x over previous
//
#include <hip/hip_runtime.h>
#include <cstdint>

typedef unsigned int uint;
typedef unsigned short ushort;

// ---------------- fast device math ----------------
__device__ __forceinline__ float fexp2(float x) { return __builtin_amdgcn_exp2f(x); }
__device__ __forceinline__ float frcp(float x)  { return __builtin_amdgcn_rcpf(x); }

__device__ __forceinline__ float fast_tanh(float x) {
    x = fminf(15.0f, fmaxf(-15.0f, x));
    float E = fexp2(x * 2.8853900817779268f);
    float d = E + 1.0f;
    float r = frcp(d);
    r = r * (2.0f - d * r);
    return (E - 1.0f) * r;
}

__device__ __forceinline__ ushort f2bf(float x) {      // RNE fp32 -> bf16
    uint u = __float_as_uint(x);
    return (ushort)((u + 0x7fffu + ((u >> 16) & 1u)) >> 16);
}
__device__ __forceinline__ uint pk2bf(float lo, float hi) {
    return (uint)f2bf(lo) | ((uint)f2bf(hi) << 16);
}

// ---------------- tiled fp32 GEMM v1 (small layers; known-good) --------------
#define BM 64
#define BN 64
#define BK 16

template<bool TANH>
__global__ __launch_bounds__(256) void gemm_bias(
    const float* __restrict__ A, const float* __restrict__ W,
    const float* __restrict__ bias, float* __restrict__ C,
    int M, int N, int K)
{
    __shared__ float As[BK][BM + 4];
    __shared__ float Bs[BK][BN + 4];

    const int tid = threadIdx.x;
    const int tx = tid & 15;
    const int ty = tid >> 4;
    const int m0 = blockIdx.y * BM;
    const int n0 = blockIdx.x * BN;

    float acc[4][4] = {};

    for (int k0 = 0; k0 < K; k0 += BK) {
        #pragma unroll
        for (int ld = 0; ld < 4; ++ld) {
            int e  = tid + ld * 256;
            int kk = e & 15, mm = e >> 4;
            int kg = k0 + kk;
            As[kk][mm] = (kg < K) ? A[(size_t)(m0 + mm) * K + kg] : 0.0f;
        }
        #pragma unroll
        for (int ld = 0; ld < 4; ++ld) {
            int e  = tid + ld * 256;
            int nn = e & 63, kk = e >> 6;
            int kg = k0 + kk, ng = n0 + nn;
            Bs[kk][nn] = (kg < K && ng < N) ? W[(size_t)kg * N + ng] : 0.0f;
        }
        __syncthreads();

        #pragma unroll
        for (int kk = 0; kk < BK; ++kk) {
            float4 a  = *(const float4*)&As[kk][ty * 4];
            float4 bq = *(const float4*)&Bs[kk][tx * 4];
            float av[4] = {a.x, a.y, a.z, a.w};
            float bv[4] = {bq.x, bq.y, bq.z, bq.w};
            #pragma unroll
            for (int i2 = 0; i2 < 4; ++i2)
                #pragma unroll
                for (int j2 = 0; j2 < 4; ++j2)
                    acc[i2][j2] += av[i2] * bv[j2];
        }
        __syncthreads();
    }

    const int cbase = n0 + tx * 4;
    if (cbase >= N) return;

    float bb[4];
    if (cbase + 3 < N) {
        float4 b4 = *(const float4*)&bias[cbase];
        bb[0] = b4.x; bb[1] = b4.y; bb[2] = b4.z; bb[3] = b4.w;
    } else {
        #pragma unroll
        for (int e = 0; e < 4; ++e) bb[e] = (cbase + e < N) ? bias[cbase + e] : 0.0f;
    }

    #pragma unroll
    for (int i2 = 0; i2 < 4; ++i2) {
        int row = m0 + ty * 4 + i2;
        float o[4];
        #pragma unroll
        for (int j2 = 0; j2 < 4; ++j2) {
            float v = acc[i2][j2] + bb[j2];
            o[j2] = TANH ? fast_tanh(v) : v;
        }
        if (cbase + 3 < N) {
            float4 o4 = {o[0], o[1], o[2], o[3]};
            *(float4*)&C[(size_t)row * N + cbase] = o4;
        } else {
            #pragma unroll
            for (int j2 = 0; j2 < 4; ++j2)
                if (cbase + j2 < N) C[(size_t)row * N + cbase + j2] = o[j2];
        }
    }
}

// ---------------- W [K][N] fp32 -> Wt [512][512] bf16 (n-major, zero-pad) ----
__global__ __launch_bounds__(256) void wt_pad(
    const float* __restrict__ W, ushort* __restrict__ out, int K, int N)
{
    int idx = blockIdx.x * 256 + threadIdx.x;   // 512*512 total
    int n = idx >> 9, k = idx & 511;
    float v = (n < N && k < K) ? W[(size_t)k * N + n] : 0.0f;
    out[idx] = f2bf(v);
}

// ---------------- MFMA bf16 GEMM: C[M][500] = act(A[M][500] @ Wt^T + bias) ---
// A fp32 (converted to bf16 in staging), Wt bf16 [512][512] n-major k-contig.
// 128x128 tile, 4 waves (2x2), wave = 64x64 via 4x4 frags of 16x16x32.
// Layouts (guide-verified): A frag row=lane&15, k=8*(lane>>4)+e;
// B frag col=lane&15 (Wt row), same k; D col=lane&15, row=4*(lane>>4)+reg.
typedef __attribute__((ext_vector_type(8))) short bf16x8;
typedef __attribute__((ext_vector_type(4))) float f32x4;

template<bool TANH>
__global__ __launch_bounds__(256) void mfma_gemm(
    const float* __restrict__ A, const ushort* __restrict__ Wt,
    const float* __restrict__ bias, float* __restrict__ C,
    int M, int N)                                  // K fixed = 500 (pad 512)
{
    __shared__ ushort As[128][40];   // [m][k] bf16, row pad 80B (2-way max)
    __shared__ ushort Bs[128][40];   // [n][k] bf16

    const int tid = threadIdx.x;
    const int l   = tid & 63;
    const int wv  = tid >> 6;
    const int wr  = wv >> 1, wc = wv & 1;
    const int m0  = blockIdx.y * 128;
    const int n0  = blockIdx.x * 128;

    const int srow = tid >> 1;        // staging row 0..127
    const int shalf = tid & 1;        // k-half 0..1 (16 elems)

    const int fr = l & 15;            // fragment row/col
    const int ko = l >> 4;            // k-oct 0..3

    f32x4 acc[4][4];
    #pragma unroll
    for (int i = 0; i < 4; ++i)
        #pragma unroll
        for (int j = 0; j < 4; ++j) acc[i][j] = (f32x4){0.f, 0.f, 0.f, 0.f};

    const float* Arow = A + (size_t)(m0 + srow) * 500;
    const ushort* Wrow = Wt + (size_t)(n0 + srow) * 512;

    for (int kc = 0; kc < 512; kc += 32) {
        // stage A: fp32 -> bf16 RNE, 16 elems/thread
        {
            int kb = kc + shalf * 16;
            float4 v0 = (kb +  3 < 500) ? *(const float4*)(Arow + kb)      : (float4){0,0,0,0};
            float4 v1 = (kb +  7 < 500) ? *(const float4*)(Arow + kb + 4)  : (float4){0,0,0,0};
            float4 v2 = (kb + 11 < 500) ? *(const float4*)(Arow + kb + 8)  : (float4){0,0,0,0};
            float4 v3 = (kb + 15 < 500) ? *(const float4*)(Arow + kb + 12) : (float4){0,0,0,0};
            uint4 p0 = {pk2bf(v0.x, v0.y), pk2bf(v0.z, v0.w), pk2bf(v1.x, v1.y), pk2bf(v1.z, v1.w)};
            uint4 p1 = {pk2bf(v2.x, v2.y), pk2bf(v2.z, v2.w), pk2bf(v3.x, v3.y), pk2bf(v3.z, v3.w)};
            *(uint4*)&As[srow][shalf * 16]     = p0;
            *(uint4*)&As[srow][shalf * 16 + 8] = p1;
            // stage B: already bf16, padded
            uint4 b0 = *(const uint4*)(Wrow + kc + shalf * 16);
            uint4 b1 = *(const uint4*)(Wrow + kc + shalf * 16 + 8);
            *(uint4*)&Bs[srow][shalf * 16]     = b0;
            *(uint4*)&Bs[srow][shalf * 16 + 8] = b1;
        }
        __syncthreads();

        bf16x8 af[4], bf[4];
        #pragma unroll
        for (int mi = 0; mi < 4; ++mi)
            af[mi] = *(const bf16x8*)&As[wr * 64 + mi * 16 + fr][ko * 8];
        #pragma unroll
        for (int ni = 0; ni < 4; ++ni)
            bf[ni] = *(const bf16x8*)&Bs[wc * 64 + ni * 16 + fr][ko * 8];

        #pragma unroll
        for (int mi = 0; mi < 4; ++mi)
            #pragma unroll
            for (int ni = 0; ni < 4; ++ni)
                acc[mi][ni] = __builtin_amdgcn_mfma_f32_16x16x32_bf16(
                    af[mi], bf[ni], acc[mi][ni], 0, 0, 0);
        __syncthreads();
    }

    // epilogue: D col=lane&15, row=4*(lane>>4)+reg
    #pragma unroll
    for (int mi = 0; mi < 4; ++mi) {
        #pragma unroll
        for (int ni = 0; ni < 4; ++ni) {
            int col = n0 + wc * 64 + ni * 16 + fr;
            if (col >= N) continue;
            float bb = bias[col];
            #pragma unroll
            for (int r = 0; r < 4; ++r) {
                int row = m0 + wr * 64 + mi * 16 + ko * 4 + r;
                float v = acc[mi][ni][r] + bb;
                C[(size_t)row * N + col] = TANH ? fast_tanh(v) : v;
            }
        }
    }
}

// ---------------- decoder layer 1 (K=4) --------------------------------------
__global__ __launch_bounds__(256) void dec_l1(
    const float* __restrict__ Mo, const float* __restrict__ Wd,
    const float* __restrict__ bd, float* __restrict__ O)
{
    int idx = blockIdx.x * 256 + threadIdx.x;
    int r  = idx / 125;
    int c4 = (idx % 125) * 4;
    float4 m = *(const float4*)&Mo[(size_t)r * 4];
    float4 w0 = *(const float4*)&Wd[0 * 500 + c4];
    float4 w1 = *(const float4*)&Wd[1 * 500 + c4];
    float4 w2 = *(const float4*)&Wd[2 * 500 + c4];
    float4 w3 = *(const float4*)&Wd[3 * 500 + c4];
    float4 b  = *(const float4*)&bd[c4];
    float o0 = b.x + m.x * w0.x + m.y * w1.x + m.z * w2.x + m.w * w3.x;
    float o1 = b.y + m.x * w0.y + m.y * w1.y + m.z * w2.y + m.w * w3.y;
    float o2 = b.z + m.x * w0.z + m.y * w1.z + m.z * w2.z + m.w * w3.z;
    float o3 = b.w + m.x * w0.w + m.y * w1.w + m.z * w2.w + m.w * w3.w;
    float4 o = {fast_tanh(o0), fast_tanh(o1), fast_tanh(o2), fast_tanh(o3)};
    *(float4*)&O[(size_t)r * 500 + c4] = o;
}

// ---------------- LTC scan: split-j butterfly (R8 exact, best: 1532us) -------
#define SEQ_T 512

__global__ __launch_bounds__(512, 2) void ltc_scan(
    const float* __restrict__ h,
    const float* __restrict__ gleak, const float* __restrict__ vleak,
    const float* __restrict__ cm,
    const float* __restrict__ w,  const float* __restrict__ mu,
    const float* __restrict__ sg, const float* __restrict__ erev,
    const float* __restrict__ sw,  const float* __restrict__ smu,
    const float* __restrict__ ssg, const float* __restrict__ serev,
    const float* __restrict__ in_w, const float* __restrict__ in_b,
    const float* __restrict__ out_w, const float* __restrict__ out_b,
    float* __restrict__ motor)
{
    const int b   = blockIdx.x;
    const int tid = threadIdx.x;
    const int w8  = tid >> 6;
    const int l   = tid & 63;
    const int jl  = l & 7;
    const int ig  = l >> 3;
    const int j   = 8 * w8 + jl;

    const float LOG2E = 1.4426950408889634f;

    __shared__ float vbuf[2][64];

    float A1[8], B1[8], Wp[8], WE[8];
    #pragma unroll
    for (int r = 0; r < 8; ++r) {
        int i = 8 * ig + r;
        float s = sg[i * 64 + j];
        A1[r] = s * LOG2E;
        B1[r] = mu[i * 64 + j] * s * LOG2E;
        Wp[r] = w[i * 64 + j];
        WE[r] = Wp[r] * erev[i * 64 + j];
    }
    float sA[3], sB[3], sWp[3], sWE[3], uw[3], ub[3];
    int   sI[3];
    #pragma unroll
    for (int r = 0; r < 3; ++r) {
        int i = ig + 8 * r;
        bool live = (i < 20);
        sI[r] = live ? i : 0;
        float s = ssg[sI[r] * 64 + j];
        sA[r]  = s * LOG2E;
        sB[r]  = smu[sI[r] * 64 + j] * s * LOG2E;
        sWp[r] = live ? sw[sI[r] * 64 + j] : 0.0f;
        sWE[r] = live ? sWp[r] * serev[sI[r] * 64 + j] : 0.0f;
        uw[r]  = in_w[sI[r]];
        ub[r]  = in_b[sI[r]];
    }

    const float cmt  = cm[j] * 6.0f;
    const float gl   = gleak[j];
    const float glvl = gl * vleak[j];
    const float gle  = cmt + gl + 1e-8f;
    const float ow   = out_w[j & 3], ob = out_b[j & 3];

    float vj = 0.0f;
    const float* hb = h + (size_t)b * SEQ_T * 20;
    float* mb = motor + (size_t)b * SEQ_T * 4;

    float u_cur[3], u_nxt[3];
    #pragma unroll
    for (int r = 0; r < 3; ++r) u_cur[r] = hb[sI[r]];

    if (tid < 64) vbuf[0][tid] = 0.0f;
    __syncthreads();

    int cur = 0;
    for (int t = 0; t < SEQ_T; ++t) {
        int tn = (t + 1 < SEQ_T) ? (t + 1) : t;
        #pragma unroll
        for (int r = 0; r < 3; ++r) u_nxt[r] = hb[tn * 20 + sI[r]];

        float ns = 0.0f, ds = 0.0f;
        #pragma unroll
        for (int r = 0; r < 3; ++r) {
            float ui = fmaf(u_cur[r], uw[r], ub[r]);
            float x  = sB[r] - ui * sA[r];
            float E  = fexp2(x);
            float s  = frcp(1.0f + E);
            ns = fmaf(sWE[r], s, ns);
            ds = fmaf(sWp[r], s, ds);
        }
        ns += __shfl_xor(ns, 8);  ds += __shfl_xor(ds, 8);
        ns += __shfl_xor(ns, 16); ds += __shfl_xor(ds, 16);
        ns += __shfl_xor(ns, 32); ds += __shfl_xor(ds, 32);

        #pragma unroll 1
        for (int uf = 0; uf < 6; ++uf) {
            float4 va = *(const float4*)&vbuf[cur][8 * ig];
            float4 vc = *(const float4*)&vbuf[cur][8 * ig + 4];
            float vv[8] = {va.x, va.y, va.z, va.w, vc.x, vc.y, vc.z, vc.w};

            float an = 0.0f, ad = 0.0f;
            #pragma unroll
            for (int r = 0; r < 8; ++r) {
                float x = fmaf(-vv[r], A1[r], B1[r]);
                float E = fexp2(x);
                float s = frcp(1.0f + E);
                an = fmaf(WE[r], s, an);
                ad = fmaf(Wp[r], s, ad);
            }
            an += __shfl_xor(an, 8);  ad += __shfl_xor(ad, 8);
            an += __shfl_xor(an, 16); ad += __shfl_xor(ad, 16);
            an += __shfl_xor(an, 32); ad += __shfl_xor(ad, 32);

            float num = fmaf(cmt, vj, glvl) + an + ns;
            float den = gle + ad + ds;
            vj = num * frcp(den);

            if (ig == 0) vbuf[cur ^ 1][j] = vj;
            __syncthreads();
            cur ^= 1;
        }

        if (w8 == 0 && ig == 0 && jl < 4) mb[t * 4 + jl] = fmaf(vj, ow, ob);

        #pragma unroll
        for (int r = 0; r < 3; ++r) u_cur[r] = u_nxt[r];
    }
}

// ---------------- launch --------------------------------------------------
extern "C" void kernel_launch(void* const* d_in, const int* in_sizes, int n_in,
                              void* d_out, int out_size, void* d_ws, size_t ws_size,
                              hipStream_t stream) {
    const float* x      = (const float*)d_in[0];
    const float* enc_w0 = (const float*)d_in[1];
    const float* enc_b0 = (const float*)d_in[2];
    const float* enc_w1 = (const float*)d_in[3];
    const float* enc_b1 = (const float*)d_in[4];
    const float* enc_w2 = (const float*)d_in[5];
    const float* enc_b2 = (const float*)d_in[6];
    const float* dec_w0 = (const float*)d_in[7];
    const float* dec_b0 = (const float*)d_in[8];
    const float* dec_w1 = (const float*)d_in[9];
    const float* dec_b1 = (const float*)d_in[10];
    const float* dec_w2 = (const float*)d_in[11];
    const float* dec_b2 = (const float*)d_in[12];
    const float* gleak  = (const float*)d_in[13];
    const float* vleak  = (const float*)d_in[14];
    const float* cm     = (const float*)d_in[15];
    const float* w      = (const float*)d_in[16];
    const float* mu     = (const float*)d_in[17];
    const float* sigma  = (const float*)d_in[18];
    const float* erev   = (const float*)d_in[19];
    const float* sw     = (const float*)d_in[20];
    const float* smu    = (const float*)d_in[21];
    const float* ssigma = (const float*)d_in[22];
    const float* serev  = (const float*)d_in[23];
    const float* in_w   = (const float*)d_in[24];
    const float* in_b   = (const float*)d_in[25];
    const float* out_w  = (const float*)d_in[26];
    const float* out_b  = (const float*)d_in[27];

    float* ws   = (float*)d_ws;
    float* buf1 = ws;                       // 16384*500 fp32
    float* buf2 = ws + 8192000;             // 16384*500 fp32
    float* hbuf = ws + 16384000;            // 16384*20 fp32 (aliased by Wt bf16)
    float* mbuf = ws + 16711680;            // 16384*4
    ushort* Wt  = (ushort*)hbuf;            // 512*512 bf16 = 0.5MB (hbuf is 1.3MB)

    dim3 blk(256);
    // encoder
    wt_pad<<<dim3(1024), blk, 0, stream>>>(enc_w1, Wt, 500, 500);
    gemm_bias<true ><<<dim3(8, 256), blk, 0, stream>>>(x, enc_w0, enc_b0, buf1, 16384, 500, 39);
    mfma_gemm<true ><<<dim3(4, 128), blk, 0, stream>>>(buf1, Wt, enc_b1, buf2, 16384, 500);
    gemm_bias<false><<<dim3(1, 256), blk, 0, stream>>>(buf2, enc_w2, enc_b2, hbuf, 16384, 20, 500);
    // LTC scan
    ltc_scan<<<dim3(32), dim3(512), 0, stream>>>(hbuf, gleak, vleak, cm, w, mu, sigma, erev,
                                                 sw, smu, ssigma, serev, in_w, in_b, out_w, out_b, mbuf);
    // decoder
    wt_pad<<<dim3(1024), blk, 0, stream>>>(dec_w1, Wt, 500, 500);   // hbuf dead after scan
    dec_l1<<<dim3(8000), blk, 0, stream>>>(mbuf, dec_w0, dec_b0, buf1);
    mfma_gemm<true ><<<dim3(4, 128), blk, 0, stream>>>(buf1, Wt, dec_b1, buf2, 16384, 500);
    gemm_bias<false><<<dim3(1, 256), blk, 0, stream>>>(buf2, dec_w2, dec_b2, (float*)d_out, 16384, 30, 500);
}

// Round 14
// 1688.934 us; speedup vs baseline: 1.4517x; 1.1107x over previous
//
#include <hip/hip_runtime.h>
#include <cstdint>

typedef unsigned int uint;
typedef unsigned short ushort;

// ---------------- fast device math ----------------
__device__ __forceinline__ float fexp2(float x) { return __builtin_amdgcn_exp2f(x); }
__device__ __forceinline__ float frcp(float x)  { return __builtin_amdgcn_rcpf(x); }

__device__ __forceinline__ float fast_tanh(float x) {
    x = fminf(15.0f, fmaxf(-15.0f, x));
    float E = fexp2(x * 2.8853900817779268f);
    float d = E + 1.0f;
    float r = frcp(d);
    r = r * (2.0f - d * r);
    return (E - 1.0f) * r;
}

__device__ __forceinline__ ushort f2bf(float x) {      // RNE fp32 -> bf16
    uint u = __float_as_uint(x);
    return (ushort)((u + 0x7fffu + ((u >> 16) & 1u)) >> 16);
}
__device__ __forceinline__ uint pk2bf(float lo, float hi) {
    return (uint)f2bf(lo) | ((uint)f2bf(hi) << 16);
}

// fast butterfly helpers (VALU instead of ds-pipe where possible)
__device__ __forceinline__ float bfly8(float x) {      // x + lane^8 (DPP row_ror:8)
    float t = __uint_as_float(__builtin_amdgcn_update_dpp(
        0, (int)__float_as_uint(x), 0x128, 0xf, 0xf, true));
    return x + t;
}
__device__ __forceinline__ float bfly32(float x) {     // x + lane^32
#if __has_builtin(__builtin_amdgcn_permlane32_swap)
    typedef unsigned int uv2 __attribute__((ext_vector_type(2)));
    uv2 r = __builtin_amdgcn_permlane32_swap(
        __float_as_uint(x), __float_as_uint(x), false, false);
    return __uint_as_float(r.x) + __uint_as_float(r.y);
#else
    return x + __shfl_xor(x, 32);
#endif
}

// ---------------- tiled fp32 GEMM v1 (dec2 output layer; known-good) ---------
#define BM 64
#define BN 64
#define BK 16

template<bool TANH>
__global__ __launch_bounds__(256) void gemm_bias(
    const float* __restrict__ A, const float* __restrict__ W,
    const float* __restrict__ bias, float* __restrict__ C,
    int M, int N, int K)
{
    __shared__ float As[BK][BM + 4];
    __shared__ float Bs[BK][BN + 4];

    const int tid = threadIdx.x;
    const int tx = tid & 15;
    const int ty = tid >> 4;
    const int m0 = blockIdx.y * BM;
    const int n0 = blockIdx.x * BN;

    float acc[4][4] = {};

    for (int k0 = 0; k0 < K; k0 += BK) {
        #pragma unroll
        for (int ld = 0; ld < 4; ++ld) {
            int e  = tid + ld * 256;
            int kk = e & 15, mm = e >> 4;
            int kg = k0 + kk;
            As[kk][mm] = (kg < K) ? A[(size_t)(m0 + mm) * K + kg] : 0.0f;
        }
        #pragma unroll
        for (int ld = 0; ld < 4; ++ld) {
            int e  = tid + ld * 256;
            int nn = e & 63, kk = e >> 6;
            int kg = k0 + kk, ng = n0 + nn;
            Bs[kk][nn] = (kg < K && ng < N) ? W[(size_t)kg * N + ng] : 0.0f;
        }
        __syncthreads();

        #pragma unroll
        for (int kk = 0; kk < BK; ++kk) {
            float4 a  = *(const float4*)&As[kk][ty * 4];
            float4 bq = *(const float4*)&Bs[kk][tx * 4];
            float av[4] = {a.x, a.y, a.z, a.w};
            float bv[4] = {bq.x, bq.y, bq.z, bq.w};
            #pragma unroll
            for (int i2 = 0; i2 < 4; ++i2)
                #pragma unroll
                for (int j2 = 0; j2 < 4; ++j2)
                    acc[i2][j2] += av[i2] * bv[j2];
        }
        __syncthreads();
    }

    const int cbase = n0 + tx * 4;
    if (cbase >= N) return;

    float bb[4];
    #pragma unroll
    for (int e = 0; e < 4; ++e) bb[e] = (cbase + e < N) ? bias[cbase + e] : 0.0f;

    #pragma unroll
    for (int i2 = 0; i2 < 4; ++i2) {
        int row = m0 + ty * 4 + i2;
        float o[4];
        #pragma unroll
        for (int j2 = 0; j2 < 4; ++j2) {
            float v = acc[i2][j2] + bb[j2];
            o[j2] = TANH ? fast_tanh(v) : v;
        }
        if (cbase + 3 < N) {
            float4 o4 = {o[0], o[1], o[2], o[3]};
            *(float4*)&C[(size_t)row * N + cbase] = o4;
        } else {
            #pragma unroll
            for (int j2 = 0; j2 < 4; ++j2)
                if (cbase + j2 < N) C[(size_t)row * N + cbase + j2] = o[j2];
        }
    }
}

// ---------------- weight prep --------------------------------------------
// prep1: Wt1e [512][512] <- enc_w1 ; Wt0e [512][64] <- enc_w0 ; Wt2e [32][512] <- enc_w2
__global__ __launch_bounds__(256) void prep1(
    const float* __restrict__ w0, const float* __restrict__ w1,
    const float* __restrict__ w2,
    ushort* __restrict__ Wt1e, ushort* __restrict__ Wt0e, ushort* __restrict__ Wt2e)
{
    int idx = blockIdx.x * 256 + threadIdx.x;
    if (idx < 262144) {
        int n = idx >> 9, k = idx & 511;
        Wt1e[idx] = f2bf((n < 500 && k < 500) ? w1[(size_t)k * 500 + n] : 0.0f);
    } else if (idx < 294912) {
        int i = idx - 262144;
        int n = i >> 6, k = i & 63;
        Wt0e[i] = f2bf((n < 500 && k < 39) ? w0[(size_t)k * 500 + n] : 0.0f);
    } else {
        int i = idx - 294912;          // < 16384
        int n = i >> 9, k = i & 511;
        Wt2e[i] = f2bf((n < 20 && k < 500) ? w2[(size_t)k * 20 + n] : 0.0f);
    }
}

// prep2 (after scan): W [K][N] fp32 -> Wt [512][512] bf16 n-major
__global__ __launch_bounds__(256) void wt_pad(
    const float* __restrict__ W, ushort* __restrict__ out, int K, int N)
{
    int idx = blockIdx.x * 256 + threadIdx.x;
    int n = idx >> 9, k = idx & 511;
    float v = (n < N && k < K) ? W[(size_t)k * N + n] : 0.0f;
    out[idx] = f2bf(v);
}

// ---------------- MFMA types ------------------------------------------------
typedef __attribute__((ext_vector_type(8))) short bf16x8;
typedef __attribute__((ext_vector_type(4))) float f32x4;

// ---------------- MFMA bf16 GEMM 128x128 (K=500 pad 512) — R13-proven --------
template<bool TANH>
__global__ __launch_bounds__(256) void mfma_gemm(
    const float* __restrict__ A, const ushort* __restrict__ Wt,
    const float* __restrict__ bias, float* __restrict__ C,
    int M, int N)
{
    __shared__ ushort As[128][40];
    __shared__ ushort Bs[128][40];

    const int tid = threadIdx.x;
    const int l   = tid & 63;
    const int wv  = tid >> 6;
    const int wr  = wv >> 1, wc = wv & 1;
    const int m0  = blockIdx.y * 128;
    const int n0  = blockIdx.x * 128;

    const int srow = tid >> 1;
    const int shalf = tid & 1;

    const int fr = l & 15;
    const int ko = l >> 4;

    f32x4 acc[4][4];
    #pragma unroll
    for (int i = 0; i < 4; ++i)
        #pragma unroll
        for (int j = 0; j < 4; ++j) acc[i][j] = (f32x4){0.f, 0.f, 0.f, 0.f};

    const float* Arow = A + (size_t)(m0 + srow) * 500;
    const ushort* Wrow = Wt + (size_t)(n0 + srow) * 512;

    for (int kc = 0; kc < 512; kc += 32) {
        {
            int kb = kc + shalf * 16;
            float4 v0 = (kb +  3 < 500) ? *(const float4*)(Arow + kb)      : (float4){0,0,0,0};
            float4 v1 = (kb +  7 < 500) ? *(const float4*)(Arow + kb + 4)  : (float4){0,0,0,0};
            float4 v2 = (kb + 11 < 500) ? *(const float4*)(Arow + kb + 8)  : (float4){0,0,0,0};
            float4 v3 = (kb + 15 < 500) ? *(const float4*)(Arow + kb + 12) : (float4){0,0,0,0};
            uint4 p0 = {pk2bf(v0.x, v0.y), pk2bf(v0.z, v0.w), pk2bf(v1.x, v1.y), pk2bf(v1.z, v1.w)};
            uint4 p1 = {pk2bf(v2.x, v2.y), pk2bf(v2.z, v2.w), pk2bf(v3.x, v3.y), pk2bf(v3.z, v3.w)};
            *(uint4*)&As[srow][shalf * 16]     = p0;
            *(uint4*)&As[srow][shalf * 16 + 8] = p1;
            uint4 b0 = *(const uint4*)(Wrow + kc + shalf * 16);
            uint4 b1 = *(const uint4*)(Wrow + kc + shalf * 16 + 8);
            *(uint4*)&Bs[srow][shalf * 16]     = b0;
            *(uint4*)&Bs[srow][shalf * 16 + 8] = b1;
        }
        __syncthreads();

        bf16x8 af[4], bf[4];
        #pragma unroll
        for (int mi = 0; mi < 4; ++mi)
            af[mi] = *(const bf16x8*)&As[wr * 64 + mi * 16 + fr][ko * 8];
        #pragma unroll
        for (int ni = 0; ni < 4; ++ni)
            bf[ni] = *(const bf16x8*)&Bs[wc * 64 + ni * 16 + fr][ko * 8];

        #pragma unroll
        for (int mi = 0; mi < 4; ++mi)
            #pragma unroll
            for (int ni = 0; ni < 4; ++ni)
                acc[mi][ni] = __builtin_amdgcn_mfma_f32_16x16x32_bf16(
                    af[mi], bf[ni], acc[mi][ni], 0, 0, 0);
        __syncthreads();
    }

    #pragma unroll
    for (int mi = 0; mi < 4; ++mi) {
        #pragma unroll
        for (int ni = 0; ni < 4; ++ni) {
            int col = n0 + wc * 64 + ni * 16 + fr;
            if (col >= N) continue;
            float bb = bias[col];
            #pragma unroll
            for (int r = 0; r < 4; ++r) {
                int row = m0 + wr * 64 + mi * 16 + ko * 4 + r;
                float v = acc[mi][ni][r] + bb;
                C[(size_t)row * N + col] = TANH ? fast_tanh(v) : v;
            }
        }
    }
}

// ---------------- MFMA enc0: K=39 (pad 64), A fp32 stride 39 -----------------
template<bool TANH>
__global__ __launch_bounds__(256) void mfma_gemm_k64(
    const float* __restrict__ A, const ushort* __restrict__ Wt,   // Wt [512][64]
    const float* __restrict__ bias, float* __restrict__ C,
    int M, int N, int KA)
{
    __shared__ ushort As[128][40];
    __shared__ ushort Bs[128][40];

    const int tid = threadIdx.x;
    const int l   = tid & 63;
    const int wv  = tid >> 6;
    const int wr  = wv >> 1, wc = wv & 1;
    const int m0  = blockIdx.y * 128;
    const int n0  = blockIdx.x * 128;

    const int srow = tid >> 1;
    const int shalf = tid & 1;
    const int fr = l & 15;
    const int ko = l >> 4;

    f32x4 acc[4][4];
    #pragma unroll
    for (int i = 0; i < 4; ++i)
        #pragma unroll
        for (int j = 0; j < 4; ++j) acc[i][j] = (f32x4){0.f, 0.f, 0.f, 0.f};

    const float* Arow = A + (size_t)(m0 + srow) * KA;
    const ushort* Wrow = Wt + (size_t)(n0 + srow) * 64;

    for (int kc = 0; kc < 64; kc += 32) {
        {
            int kb = kc + shalf * 16;
            uint pk[8];
            #pragma unroll
            for (int e = 0; e < 8; ++e) {
                int k2 = kb + 2 * e;
                float lo = (k2     < KA) ? Arow[k2]     : 0.0f;
                float hi = (k2 + 1 < KA) ? Arow[k2 + 1] : 0.0f;
                pk[e] = pk2bf(lo, hi);
            }
            *(uint4*)&As[srow][shalf * 16]     = *(uint4*)&pk[0];
            *(uint4*)&As[srow][shalf * 16 + 8] = *(uint4*)&pk[4];
            *(uint4*)&Bs[srow][shalf * 16]     = *(const uint4*)(Wrow + kc + shalf * 16);
            *(uint4*)&Bs[srow][shalf * 16 + 8] = *(const uint4*)(Wrow + kc + shalf * 16 + 8);
        }
        __syncthreads();

        bf16x8 af[4], bf[4];
        #pragma unroll
        for (int mi = 0; mi < 4; ++mi)
            af[mi] = *(const bf16x8*)&As[wr * 64 + mi * 16 + fr][ko * 8];
        #pragma unroll
        for (int ni = 0; ni < 4; ++ni)
            bf[ni] = *(const bf16x8*)&Bs[wc * 64 + ni * 16 + fr][ko * 8];

        #pragma unroll
        for (int mi = 0; mi < 4; ++mi)
            #pragma unroll
            for (int ni = 0; ni < 4; ++ni)
                acc[mi][ni] = __builtin_amdgcn_mfma_f32_16x16x32_bf16(
                    af[mi], bf[ni], acc[mi][ni], 0, 0, 0);
        __syncthreads();
    }

    #pragma unroll
    for (int mi = 0; mi < 4; ++mi) {
        #pragma unroll
        for (int ni = 0; ni < 4; ++ni) {
            int col = n0 + wc * 64 + ni * 16 + fr;
            if (col >= N) continue;
            float bb = bias[col];
            #pragma unroll
            for (int r = 0; r < 4; ++r) {
                int row = m0 + wr * 64 + mi * 16 + ko * 4 + r;
                float v = acc[mi][ni][r] + bb;
                C[(size_t)row * N + col] = TANH ? fast_tanh(v) : v;
            }
        }
    }
}

// ---------------- MFMA enc2: N=20 (pad 32), 128x32 tile, linear --------------
__global__ __launch_bounds__(256) void mfma_gemm_n32(
    const float* __restrict__ A, const ushort* __restrict__ Wt,   // Wt [32][512]
    const float* __restrict__ bias, float* __restrict__ C,
    int M, int N)                                  // A stride 500, C stride N
{
    __shared__ ushort As[128][40];
    __shared__ ushort Bs[32][40];

    const int tid = threadIdx.x;
    const int l   = tid & 63;
    const int wv  = tid >> 6;          // wave = m-quadrant
    const int m0  = blockIdx.y * 128;

    const int srow = tid >> 1;
    const int shalf = tid & 1;
    const int fr = l & 15;
    const int ko = l >> 4;

    f32x4 acc[2][2];
    #pragma unroll
    for (int i = 0; i < 2; ++i)
        #pragma unroll
        for (int j = 0; j < 2; ++j) acc[i][j] = (f32x4){0.f, 0.f, 0.f, 0.f};

    const float* Arow = A + (size_t)(m0 + srow) * 500;

    for (int kc = 0; kc < 512; kc += 32) {
        {
            int kb = kc + shalf * 16;
            float4 v0 = (kb +  3 < 500) ? *(const float4*)(Arow + kb)      : (float4){0,0,0,0};
            float4 v1 = (kb +  7 < 500) ? *(const float4*)(Arow + kb + 4)  : (float4){0,0,0,0};
            float4 v2 = (kb + 11 < 500) ? *(const float4*)(Arow + kb + 8)  : (float4){0,0,0,0};
            float4 v3 = (kb + 15 < 500) ? *(const float4*)(Arow + kb + 12) : (float4){0,0,0,0};
            uint4 p0 = {pk2bf(v0.x, v0.y), pk2bf(v0.z, v0.w), pk2bf(v1.x, v1.y), pk2bf(v1.z, v1.w)};
            uint4 p1 = {pk2bf(v2.x, v2.y), pk2bf(v2.z, v2.w), pk2bf(v3.x, v3.y), pk2bf(v3.z, v3.w)};
            *(uint4*)&As[srow][shalf * 16]     = p0;
            *(uint4*)&As[srow][shalf * 16 + 8] = p1;
            if (tid < 64) {
                int br = tid >> 1, bh = tid & 1;
                const ushort* Wr = Wt + (size_t)br * 512 + kc + bh * 16;
                *(uint4*)&Bs[br][bh * 16]     = *(const uint4*)(Wr);
                *(uint4*)&Bs[br][bh * 16 + 8] = *(const uint4*)(Wr + 8);
            }
        }
        __syncthreads();

        bf16x8 af[2], bf[2];
        #pragma unroll
        for (int mi = 0; mi < 2; ++mi)
            af[mi] = *(const bf16x8*)&As[wv * 32 + mi * 16 + fr][ko * 8];
        #pragma unroll
        for (int ni = 0; ni < 2; ++ni)
            bf[ni] = *(const bf16x8*)&Bs[ni * 16 + fr][ko * 8];

        #pragma unroll
        for (int mi = 0; mi < 2; ++mi)
            #pragma unroll
            for (int ni = 0; ni < 2; ++ni)
                acc[mi][ni] = __builtin_amdgcn_mfma_f32_16x16x32_bf16(
                    af[mi], bf[ni], acc[mi][ni], 0, 0, 0);
        __syncthreads();
    }

    #pragma unroll
    for (int mi = 0; mi < 2; ++mi) {
        #pragma unroll
        for (int ni = 0; ni < 2; ++ni) {
            int col = ni * 16 + fr;
            if (col >= N) continue;
            float bb = bias[col];
            #pragma unroll
            for (int r = 0; r < 4; ++r) {
                int row = m0 + wv * 32 + mi * 16 + ko * 4 + r;
                C[(size_t)row * N + col] = acc[mi][ni][r] + bb;
            }
        }
    }
}

// ---------------- decoder layer 1 (K=4) --------------------------------------
__global__ __launch_bounds__(256) void dec_l1(
    const float* __restrict__ Mo, const float* __restrict__ Wd,
    const float* __restrict__ bd, float* __restrict__ O)
{
    int idx = blockIdx.x * 256 + threadIdx.x;
    int r  = idx / 125;
    int c4 = (idx % 125) * 4;
    float4 m = *(const float4*)&Mo[(size_t)r * 4];
    float4 w0 = *(const float4*)&Wd[0 * 500 + c4];
    float4 w1 = *(const float4*)&Wd[1 * 500 + c4];
    float4 w2 = *(const float4*)&Wd[2 * 500 + c4];
    float4 w3 = *(const float4*)&Wd[3 * 500 + c4];
    float4 b  = *(const float4*)&bd[c4];
    float o0 = b.x + m.x * w0.x + m.y * w1.x + m.z * w2.x + m.w * w3.x;
    float o1 = b.y + m.x * w0.y + m.y * w1.y + m.z * w2.y + m.w * w3.y;
    float o2 = b.z + m.x * w0.z + m.y * w1.z + m.z * w2.z + m.w * w3.z;
    float o3 = b.w + m.x * w0.w + m.y * w1.w + m.z * w2.w + m.w * w3.w;
    float4 o = {fast_tanh(o0), fast_tanh(o1), fast_tanh(o2), fast_tanh(o3)};
    *(float4*)&O[(size_t)r * 500 + c4] = o;
}

// ---------------- LTC scan: split-j butterfly + VALU butterfly levels --------
#define SEQ_T 512

__global__ __launch_bounds__(512, 2) void ltc_scan(
    const float* __restrict__ h,
    const float* __restrict__ gleak, const float* __restrict__ vleak,
    const float* __restrict__ cm,
    const float* __restrict__ w,  const float* __restrict__ mu,
    const float* __restrict__ sg, const float* __restrict__ erev,
    const float* __restrict__ sw,  const float* __restrict__ smu,
    const float* __restrict__ ssg, const float* __restrict__ serev,
    const float* __restrict__ in_w, const float* __restrict__ in_b,
    const float* __restrict__ out_w, const float* __restrict__ out_b,
    float* __restrict__ motor)
{
    const int b   = blockIdx.x;
    const int tid = threadIdx.x;
    const int w8  = tid >> 6;
    const int l   = tid & 63;
    const int jl  = l & 7;
    const int ig  = l >> 3;
    const int j   = 8 * w8 + jl;

    const float LOG2E = 1.4426950408889634f;

    __shared__ float vbuf[2][64];

    float A1[8], B1[8], Wp[8], WE[8];
    #pragma unroll
    for (int r = 0; r < 8; ++r) {
        int i = 8 * ig + r;
        float s = sg[i * 64 + j];
        A1[r] = s * LOG2E;
        B1[r] = mu[i * 64 + j] * s * LOG2E;
        Wp[r] = w[i * 64 + j];
        WE[r] = Wp[r] * erev[i * 64 + j];
    }
    float sA[3], sB[3], sWp[3], sWE[3], uw[3], ub[3];
    int   sI[3];
    #pragma unroll
    for (int r = 0; r < 3; ++r) {
        int i = ig + 8 * r;
        bool live = (i < 20);
        sI[r] = live ? i : 0;
        float s = ssg[sI[r] * 64 + j];
        sA[r]  = s * LOG2E;
        sB[r]  = smu[sI[r] * 64 + j] * s * LOG2E;
        sWp[r] = live ? sw[sI[r] * 64 + j] : 0.0f;
        sWE[r] = live ? sWp[r] * serev[sI[r] * 64 + j] : 0.0f;
        uw[r]  = in_w[sI[r]];
        ub[r]  = in_b[sI[r]];
    }

    const float cmt  = cm[j] * 6.0f;
    const float gl   = gleak[j];
    const float glvl = gl * vleak[j];
    const float gle  = cmt + gl + 1e-8f;
    const float ow   = out_w[j & 3], ob = out_b[j & 3];

    float vj = 0.0f;
    const float* hb = h + (size_t)b * SEQ_T * 20;
    float* mb = motor + (size_t)b * SEQ_T * 4;

    float u_cur[3], u_nxt[3];
    #pragma unroll
    for (int r = 0; r < 3; ++r) u_cur[r] = hb[sI[r]];

    if (tid < 64) vbuf[0][tid] = 0.0f;
    __syncthreads();

    int cur = 0;
    for (int t = 0; t < SEQ_T; ++t) {
        int tn = (t + 1 < SEQ_T) ? (t + 1) : t;
        #pragma unroll
        for (int r = 0; r < 3; ++r) u_nxt[r] = hb[tn * 20 + sI[r]];

        float ns = 0.0f, ds = 0.0f;
        #pragma unroll
        for (int r = 0; r < 3; ++r) {
            float ui = fmaf(u_cur[r], uw[r], ub[r]);
            float x  = sB[r] - ui * sA[r];
            float E  = fexp2(x);
            float s  = frcp(1.0f + E);
            ns = fmaf(sWE[r], s, ns);
            ds = fmaf(sWp[r], s, ds);
        }
        ns = bfly8(ns);  ds = bfly8(ds);
        ns += __shfl_xor(ns, 16); ds += __shfl_xor(ds, 16);
        ns = bfly32(ns); ds = bfly32(ds);

        #pragma unroll 1
        for (int uf = 0; uf < 6; ++uf) {
            float4 va = *(const float4*)&vbuf[cur][8 * ig];
            float4 vc = *(const float4*)&vbuf[cur][8 * ig + 4];
            float vv[8] = {va.x, va.y, va.z, va.w, vc.x, vc.y, vc.z, vc.w};

            float an = 0.0f, ad = 0.0f;
            #pragma unroll
            for (int r = 0; r < 8; ++r) {
                float x = fmaf(-vv[r], A1[r], B1[r]);
                float E = fexp2(x);
                float s = frcp(1.0f + E);
                an = fmaf(WE[r], s, an);
                ad = fmaf(Wp[r], s, ad);
            }
            // butterfly over ig bits: 8 via DPP, 16 via shfl, 32 via permlane
            an = bfly8(an);  ad = bfly8(ad);
            an += __shfl_xor(an, 16); ad += __shfl_xor(ad, 16);
            an = bfly32(an); ad = bfly32(ad);

            float num = fmaf(cmt, vj, glvl) + an + ns;
            float den = gle + ad + ds;
            vj = num * frcp(den);

            if (ig == 0) vbuf[cur ^ 1][j] = vj;
            __syncthreads();
            cur ^= 1;
        }

        if (w8 == 0 && ig == 0 && jl < 4) mb[t * 4 + jl] = fmaf(vj, ow, ob);

        #pragma unroll
        for (int r = 0; r < 3; ++r) u_cur[r] = u_nxt[r];
    }
}

// ---------------- launch --------------------------------------------------
extern "C" void kernel_launch(void* const* d_in, const int* in_sizes, int n_in,
                              void* d_out, int out_size, void* d_ws, size_t ws_size,
                              hipStream_t stream) {
    const float* x      = (const float*)d_in[0];
    const float* enc_w0 = (const float*)d_in[1];
    const float* enc_b0 = (const float*)d_in[2];
    const float* enc_w1 = (const float*)d_in[3];
    const float* enc_b1 = (const float*)d_in[4];
    const float* enc_w2 = (const float*)d_in[5];
    const float* enc_b2 = (const float*)d_in[6];
    const float* dec_w0 = (const float*)d_in[7];
    const float* dec_b0 = (const float*)d_in[8];
    const float* dec_w1 = (const float*)d_in[9];
    const float* dec_b1 = (const float*)d_in[10];
    const float* dec_w2 = (const float*)d_in[11];
    const float* dec_b2 = (const float*)d_in[12];
    const float* gleak  = (const float*)d_in[13];
    const float* vleak  = (const float*)d_in[14];
    const float* cm     = (const float*)d_in[15];
    const float* w      = (const float*)d_in[16];
    const float* mu     = (const float*)d_in[17];
    const float* sigma  = (const float*)d_in[18];
    const float* erev   = (const float*)d_in[19];
    const float* sw     = (const float*)d_in[20];
    const float* smu    = (const float*)d_in[21];
    const float* ssigma = (const float*)d_in[22];
    const float* serev  = (const float*)d_in[23];
    const float* in_w   = (const float*)d_in[24];
    const float* in_b   = (const float*)d_in[25];
    const float* out_w  = (const float*)d_in[26];
    const float* out_b  = (const float*)d_in[27];

    float* ws   = (float*)d_ws;
    float* buf1 = ws;                       // 16384*500 fp32
    float* buf2 = ws + 8192000;             // 16384*500 fp32
    float* hbuf = ws + 16384000;            // 16384*20 fp32 (region shared w/ Wt*)
    float* mbuf = ws + 16711680;            // 16384*4   (region shared w/ Wt2e)

    ushort* hb16 = (ushort*)hbuf;
    ushort* Wt1e = hb16;                    // 262144 u16 (dead before enc2 writes h)
    ushort* Wt0e = hb16 + 262144;           // 32768 u16  (dead before enc2)
    ushort* Wt2e = (ushort*)mbuf;           // 16384 u16  (dead before scan writes motor)
    ushort* Wt1d = hb16;                    // prepped after scan reads h

    dim3 blk(256);
    // prep + encoder
    prep1<<<dim3(1216), blk, 0, stream>>>(enc_w0, enc_w1, enc_w2, Wt1e, Wt0e, Wt2e);
    mfma_gemm_k64<true><<<dim3(4, 128), blk, 0, stream>>>(x, Wt0e, enc_b0, buf1, 16384, 500, 39);
    mfma_gemm<true><<<dim3(4, 128), blk, 0, stream>>>(buf1, Wt1e, enc_b1, buf2, 16384, 500);
    mfma_gemm_n32<<<dim3(1, 128), blk, 0, stream>>>(buf2, Wt2e, enc_b2, hbuf, 16384, 20);
    // LTC scan
    ltc_scan<<<dim3(32), dim3(512), 0, stream>>>(hbuf, gleak, vleak, cm, w, mu, sigma, erev,
                                                 sw, smu, ssigma, serev, in_w, in_b, out_w, out_b, mbuf);
    // decoder
    wt_pad<<<dim3(1024), blk, 0, stream>>>(dec_w1, Wt1d, 500, 500);
    dec_l1<<<dim3(8000), blk, 0, stream>>>(mbuf, dec_w0, dec_b0, buf1);
    mfma_gemm<true><<<dim3(4, 128), blk, 0, stream>>>(buf1, Wt1d, dec_b1, buf2, 16384, 500);
    gemm_bias<false><<<dim3(1, 256), blk, 0, stream>>>(buf2, dec_w2, dec_b2, (float*)d_out, 16384, 30, 500);
}